// Round 18
// baseline (106.361 us; speedup 1.0000x reference)
//
#include <hip/hip_runtime.h>

#define NPTS 16384
#define TH 33.33f

typedef __attribute__((ext_vector_type(8))) __bf16 bf16x8;
typedef __attribute__((ext_vector_type(4))) float  f32x4;

__device__ __forceinline__ unsigned short f2bf(float x) {
    unsigned u = __float_as_uint(x);
    u += 0x7FFFu + ((u >> 16) & 1u);
    return (unsigned short)(u >> 16);
}
__device__ __forceinline__ float bf2f(unsigned short h) {
    return __uint_as_float(((unsigned)h) << 16);
}

union UV { uint4 v; bf16x8 h; unsigned short s[8]; };

// === R18: 16x16x32 MFMA (4-reg C/D) to break the R17 occupancy wall ===
// 32x32 shape pinned acc at 32 regs/wave -> 4 waves/EU max (R10/R13/R14 spills).
// 16x16x32: acc 8 + afrag 8 + q 8 + t 8 + misc ~20 ~= 52 -> (256,8), 32 waves/CU.
// ws: mats ushort[2b][2set][2role][16384 pts][16]  (4 MB; per tile: 32 lanes x 8 bf16)
//     harr float[2b][2set][NPTS] (256 KB); d2part float[4db][128 rb][8 seg][128] (2 MB)
// k-vector (slots 0-11, rest 0):  A: [qh3, ql3, qh3, 1,1,1]   B: [ph3, ph3, pl3, -hp3]
//   => s = qh.ph + ql.ph + qh.pl - hp ~= q.p - hp ;  d^2 = 2*(hq - s)   (champion numerics)
// 16x16x32 maps: A/B k = (lane>>4)*8 + j (symmetric); C/D col=lane&15, row=(lane>>4)*4+reg
//   [m89/m91 HW-verified]. Lanes 32-63 (k 16-31): afrag=0 so B side may hold any finite
//   data (0*finite=0); q reads lane&31 (same-address pairs = free LDS broadcast).
// Ledger rules kept: no inline asm on MFMA results (R5/R7); no __shfl on acc (R16 AGPR tax);
//   LDS-scratch epilogue; staging via global_load_lds DMA (zero staging regs).

__global__ __launch_bounds__(256) void prep_kernel(const float* __restrict__ src,
        const float* __restrict__ tgt, unsigned short* __restrict__ mats,
        float* __restrict__ harr, float* __restrict__ out) {
    int t = blockIdx.x * 256 + threadIdx.x;       // 65536 threads
    if (t < 2) out[t] = 0.0f;
    int b = t >> 15, set = (t >> 14) & 1, p = t & (NPTS - 1);
    const float* pc = (set ? tgt : src) + ((size_t)b * NPTS + p) * 3;
    float x = pc[0], y = pc[1], z = pc[2];
    float hp = 0.5f * fmaf(z, z, fmaf(y, y, x * x));
    harr[(b * 2 + set) * NPTS + p] = hp;
    unsigned short xh = f2bf(x), yh = f2bf(y), zh = f2bf(z);
    unsigned short xl = f2bf(x - bf2f(xh)), yl = f2bf(y - bf2f(yh)), zl = f2bf(z - bf2f(zh));
    float rr = hp;
    unsigned short h0 = f2bf(rr); rr -= bf2f(h0);
    unsigned short h1 = f2bf(rr); rr -= bf2f(h1);
    unsigned short h2 = f2bf(rr);
    unsigned short n0 = h0 ^ 0x8000, n1 = h1 ^ 0x8000, n2 = h2 ^ 0x8000;
    const unsigned short one = 0x3F80;
    UV a0, a1, c0, c1;
    a0.s[0]=xh; a0.s[1]=yh; a0.s[2]=zh; a0.s[3]=xl; a0.s[4]=yl; a0.s[5]=zl; a0.s[6]=xh; a0.s[7]=yh;
    a1.s[0]=zh; a1.s[1]=one; a1.s[2]=one; a1.s[3]=one; a1.s[4]=0; a1.s[5]=0; a1.s[6]=0; a1.s[7]=0;
    c0.s[0]=xh; c0.s[1]=yh; c0.s[2]=zh; c0.s[3]=xh; c0.s[4]=yh; c0.s[5]=zh; c0.s[6]=xl; c0.s[7]=yl;
    c1.s[0]=zl; c1.s[1]=n0;  c1.s[2]=n1;  c1.s[3]=n2;  c1.s[4]=0; c1.s[5]=0; c1.s[6]=0; c1.s[7]=0;
    size_t tile = p >> 4; int m = p & 15;
    size_t baseA = ((size_t)((b * 2 + set) * 2 + 0)) * NPTS * 16;
    size_t baseB = ((size_t)((b * 2 + set) * 2 + 1)) * NPTS * 16;
    *(uint4*)(mats + baseA + tile * 256 + m * 8)        = a0.v;   // lane m   (g=0, k 0-7)
    *(uint4*)(mats + baseA + tile * 256 + (16 + m) * 8) = a1.v;   // lane 16+m (g=1, k 8-15)
    *(uint4*)(mats + baseB + tile * 256 + m * 8)        = c0.v;
    *(uint4*)(mats + baseB + tile * 256 + (16 + m) * 8) = c1.v;
}

#define FOLDPAIR(MM, AA) { \
    f32x4 t0 = __builtin_amdgcn_mfma_f32_16x16x32_bf16(AA, q0, zc, 0, 0, 0); \
    f32x4 t1 = __builtin_amdgcn_mfma_f32_16x16x32_bf16(AA, q1, zc, 0, 0, 0); \
    _Pragma("unroll") for (int j = 0; j < 4; j++) MM[j] = fmaxf(fmaxf(t0[j], t1[j]), MM[j]); }

#define LOAD_CHUNK(CC, BUF) { \
    const char* gb = Bseg + (size_t)(CC) * 8192; \
    char* lb = (char*)smem + (BUF) * 8192; \
    _Pragma("unroll") for (int i = 0; i < 2; i++) \
        __builtin_amdgcn_global_load_lds( \
            (const __attribute__((address_space(1))) unsigned int*)(gb + i * 4096 + tid * 16), \
            (__attribute__((address_space(3))) unsigned int*)(lb + i * 4096 + tid * 16), \
            16, 0, 0); }

__global__ __launch_bounds__(256, 8) void chamfer_kernel(
        const unsigned short* __restrict__ mats, const float* __restrict__ harr,
        float* __restrict__ d2part)
{
    const int db = blockIdx.y, dir = db >> 1, b = db & 1;
    const int rowblock = blockIdx.x >> 3, seg = blockIdx.x & 7;   // 128 rb x 8 segs
    const int tid = threadIdx.x, wave = tid >> 6, lane = tid & 63;
    const unsigned short* Am = mats + ((size_t)((b * 2 + dir) * 2 + 0)) * NPTS * 16;
    const unsigned short* Bm = mats + ((size_t)((b * 2 + (1 - dir)) * 2 + 1)) * NPTS * 16;

    __shared__ alignas(16) unsigned char smem[16384];   // 2 x 8 KB stage; epilogue scratch alias

    // ---- A fragments: 2 row-tiles (32 rows) per wave; lanes 32-63 = 0 (k 16-31 dead) ----
    const int rt0 = rowblock * 8 + wave * 2;
    UV zf; zf.v = make_uint4(0, 0, 0, 0);
    bf16x8 afrag[2] = { zf.h, zf.h };
#pragma unroll
    for (int i = 0; i < 2; i++)
        if (lane < 32) afrag[i] = *(const bf16x8*)(Am + (size_t)(rt0 + i) * 256 + lane * 8);

    f32x4 m0 = { -3.0e38f, -3.0e38f, -3.0e38f, -3.0e38f };
    f32x4 m1 = m0;
    const f32x4 zc = { 0.0f, 0.0f, 0.0f, 0.0f };

    const char* Bseg = (const char*)Bm + (size_t)seg * 65536;   // 128 col-tiles (2048 cols)

    LOAD_CHUNK(0, 0)
    __syncthreads();
#pragma unroll 1
    for (int c = 0; c < 8; ++c) {                 // 8 chunks x 16 col-tiles (256 cols)
        if (c < 7) LOAD_CHUNK(c + 1, (c + 1) & 1) // async DMA; drains at the next barrier
        const unsigned short* bb = (const unsigned short*)(smem + (c & 1) * 8192);
#pragma unroll 1
        for (int pt = 0; pt < 8; ++pt) {          // 2 col-tiles per iter
            const unsigned short* qb = bb + pt * 512 + (lane & 31) * 8;  // dup addr = broadcast
            bf16x8 q0 = *(const bf16x8*)(qb);
            bf16x8 q1 = *(const bf16x8*)(qb + 256);
            FOLDPAIR(m0, afrag[0])
            FOLDPAIR(m1, afrag[1])
        }
        __syncthreads();
    }

    // ---- epilogue: acc -> padded LDS (per-wave region) -> per-lane row reduce ----
    float* sc = (float*)smem + wave * 544;        // 2 tiles x 16 rows x 17 = 544 floats/wave
    const int g4 = lane >> 4, cc = lane & 15;
#pragma unroll
    for (int j = 0; j < 4; j++) {
        int row = g4 * 4 + j;                     // C/D map [m89/m91]
        sc[row * 17 + cc]       = m0[j];
        sc[272 + row * 17 + cc] = m1[j];
    }
    // same-wave LDS write->read: ordered by lgkmcnt (no barrier; no cross-wave sharing)
    if (lane < 32) {
        int tl = lane >> 4, r = lane & 15;
        const float* sr = sc + tl * 272 + r * 17;
        float mx = sr[0];
#pragma unroll
        for (int k = 1; k < 16; k++) mx = fmaxf(mx, sr[k]);
        int grow = (rt0 + tl) * 16 + r;
        float hq = harr[(b * 2 + dir) * NPTS + grow];
        float d2 = 2.0f * (hq - mx);
        float d = fminf(sqrtf(fmaxf(d2, 0.0f)), TH);
        float* dst = d2part + (((size_t)(db * 128 + rowblock)) * 8 + seg) * 128;
        dst[wave * 32 + lane] = d;
    }
}

__global__ __launch_bounds__(256) void merge_kernel(const float* __restrict__ d2part,
                                                    float* __restrict__ out) {
    const int b = blockIdx.y;                     // batch
    const int slice = blockIdx.x;                 // 16 slices of 1024 rows
    const int tid = threadIdx.x;
    float s = 0.0f;
#pragma unroll
    for (int pass = 0; pass < 2; pass++) {        // dir 0 and dir 1
        const float* base = d2part + (size_t)(pass * 2 + b) * 128 * 8 * 128;
#pragma unroll
        for (int i = 0; i < 4; i++) {
            int r = slice * 1024 + i * 256 + tid;
            const float* p = base + (size_t)(r >> 7) * 1024 + (r & 127);
            float m = p[0];
#pragma unroll
            for (int sgi = 1; sgi < 8; sgi++) m = fminf(m, p[sgi * 128]);
            s += m;
        }
    }
#pragma unroll
    for (int off = 32; off > 0; off >>= 1) s += __shfl_down(s, off, 64);
    __shared__ float w[4];
    if ((tid & 63) == 0) w[tid >> 6] = s;
    __syncthreads();
    if (tid == 0) {
        float t = (w[0] + w[1]) + (w[2] + w[3]);
        atomicAdd(&out[b], t * (1.0f / (2.0f * NPTS)));  // (mean_fwd + mean_bwd) / 2
    }
}

extern "C" void kernel_launch(void* const* d_in, const int* in_sizes, int n_in,
                              void* d_out, int out_size, void* d_ws, size_t ws_size,
                              hipStream_t stream) {
    const float* src = (const float*)d_in[0];
    const float* tgt = (const float*)d_in[1];
    float* out = (float*)d_out;
    unsigned short* mats = (unsigned short*)d_ws;                            // 4 MB
    float* harr = (float*)((char*)d_ws + 4194304);                           // 256 KB
    float* d2part = (float*)((char*)d_ws + 4194304 + 262144);                // 2 MB, write-once

    prep_kernel<<<256, 256, 0, stream>>>(src, tgt, mats, harr, out);
    chamfer_kernel<<<dim3(1024, 4), 256, 0, stream>>>(mats, harr, d2part);
    merge_kernel<<<dim3(16, 2), 256, 0, stream>>>(d2part, out);
}

// Round 20
// 95.261 us; speedup vs baseline: 1.1165x; 1.1165x over previous
//
#include <hip/hip_runtime.h>

#define NPTS 16384
#define TH 33.33f

typedef __attribute__((ext_vector_type(8)))  __bf16 bf16x8;
typedef __attribute__((ext_vector_type(16))) float  f32x16;

__device__ __forceinline__ unsigned short f2bf(float x) {
    unsigned u = __float_as_uint(x);
    u += 0x7FFFu + ((u >> 16) & 1u);
    return (unsigned short)(u >> 16);
}
__device__ __forceinline__ float bf2f(unsigned short h) {
    return __uint_as_float(((unsigned)h) << 16);
}

union UV { uint4 v; bf16x8 h; unsigned short s[8]; };

// === R20: single-matrix symmetric chamfer (R19 + staging BUF fix: (c+1)&1) ===
// R19 FAILED from ONE token: CONV_WRITE(c+1) wrote smem+32K/48K out of bounds,
// clobbering colsmax. Algorithm unchanged and desk-verified:
// s = q.p - hp - hq  (k slots: [0-2] qh*ph, [3-5] ql*ph, [6-8] qh*pl, [9-11] 1*(-hp),
// [12-14] (-hq)*1, [15] 0)  =>  d^2 = -2s ;  s <= 0 by AM-GM, bias +256 keeps biased
// keys positive (d2max ~ 243 here) -> uint-ordered. Row-max -> dir0; col-max -> dir1.
// Cols: TREE16 per lane (covers 16 of 32 rows; both g-halves atomicMax the same slot),
// per-chunk flush -> global atomicMin on clamped-dist bits (colmin_g, memset 0xFF).
//
// LEDGER: (256,4) = 128 unified regs, peak ~99. No inline asm on MFMA results (R5/R7).
// No __shfl on long-lived acc (R16). Staging lane-consecutive-16B (R11). pt unroll 1
// (R14/R15). 32x32x16 only (R18: 16x16 half-dead-K doubles per-CU MFMA cost).

#define TREE16(R, T) { \
    float u0 = fmaxf(T[0], T[8]),  u1 = fmaxf(T[1], T[9]); \
    float u2 = fmaxf(T[2], T[10]), u3 = fmaxf(T[3], T[11]); \
    float u4 = fmaxf(T[4], T[12]), u5 = fmaxf(T[5], T[13]); \
    float u6 = fmaxf(T[6], T[14]), u7 = fmaxf(T[7], T[15]); \
    u0 = fmaxf(u0, u4); u1 = fmaxf(u1, u5); u2 = fmaxf(u2, u6); u3 = fmaxf(u3, u7); \
    u0 = fmaxf(u0, u2); u1 = fmaxf(u1, u3); \
    R = fmaxf(u0, u1); }

#define FOLDC(MM, AA, CA, CB) { \
    f32x16 t0 = __builtin_amdgcn_mfma_f32_32x32x16_bf16(AA, q0, zc, 0, 0, 0); \
    f32x16 t1 = __builtin_amdgcn_mfma_f32_32x32x16_bf16(AA, q1, zc, 0, 0, 0); \
    _Pragma("unroll") for (int j = 0; j < 16; j++) MM[j] = fmaxf(fmaxf(t0[j], t1[j]), MM[j]); \
    float ra, rb; \
    TREE16(ra, t0) \
    TREE16(rb, t1) \
    CA = fmaxf(CA, ra); CB = fmaxf(CB, rb); }

__device__ __forceinline__ void conv_store(unsigned short* lb, int k,
                                           float x, float y, float z) {
    float hp = 0.5f * fmaf(z, z, fmaf(y, y, x * x));
    unsigned short xh = f2bf(x), yh = f2bf(y), zh = f2bf(z);
    unsigned short xl = f2bf(x - bf2f(xh)), yl = f2bf(y - bf2f(yh)), zl = f2bf(z - bf2f(zh));
    float rr = hp;
    unsigned short h0 = f2bf(rr); rr -= bf2f(h0);
    unsigned short h1 = f2bf(rr); rr -= bf2f(h1);
    unsigned short h2 = f2bf(rr);
    const unsigned short one = 0x3F80;
    UV c0, c1;
    c0.s[0]=xh; c0.s[1]=yh; c0.s[2]=zh; c0.s[3]=xh; c0.s[4]=yh; c0.s[5]=zh; c0.s[6]=xl; c0.s[7]=yl;
    c1.s[0]=zl; c1.s[1]=(unsigned short)(h0^0x8000); c1.s[2]=(unsigned short)(h1^0x8000);
    c1.s[3]=(unsigned short)(h2^0x8000); c1.s[4]=one; c1.s[5]=one; c1.s[6]=one; c1.s[7]=0;
    int t = k >> 5, pos = k & 31;
    *(uint4*)(lb + t * 512 + pos * 8)       = c0.v;   // lanes consecutive-16B: conflict-free
    *(uint4*)(lb + t * 512 + 256 + pos * 8) = c1.v;
}

#define LOAD_PTS(CC) { \
    const float* g0 = pp + (size_t)(seg * 2048 + (CC) * 512 + tid) * 3; \
    px0 = g0[0]; py0 = g0[1]; pz0 = g0[2]; \
    const float* g1 = g0 + 768; \
    px1 = g1[0]; py1 = g1[1]; pz1 = g1[2]; }

#define CONV_WRITE(BUF) { \
    unsigned short* lb = (unsigned short*)(smem + (BUF) * 16384); \
    conv_store(lb, tid,       px0, py0, pz0); \
    conv_store(lb, tid + 256, px1, py1, pz1); }

// row epilogue (champion form; d^2 = -2*mx — hq already inside s)
#define EPILOG(MM, P) { \
    float* sc = scratch + wave * 1056; \
    _Pragma("unroll") for (int j = 0; j < 16; j++) { \
        int r0 = (j & 3) + 8 * (j >> 2) + 4 * g; sc[r0 * 33 + cc] = MM[j]; } \
    __syncthreads(); \
    const float* sr = sc + cc * 33 + g * 16; \
    float mx = -3.0e38f; \
    _Pragma("unroll") for (int k = 0; k < 16; k++) mx = fmaxf(mx, sr[k]); \
    mx = fmaxf(mx, __shfl_xor(mx, 32, 64)); \
    if (lane < 32) { \
        float d2 = -2.0f * mx; \
        float d = fminf(sqrtf(fmaxf(d2, 0.0f)), TH); \
        dst[wave * 64 + (P) * 32 + lane] = d; } \
    __syncthreads(); }

__global__ __launch_bounds__(256, 4) void chamfer_kernel(
        const float* __restrict__ src, const float* __restrict__ tgt,
        float* __restrict__ row_part, unsigned int* __restrict__ colmin_g,
        float* __restrict__ out)
{
    const int b = blockIdx.y;
    const int rowblock = blockIdx.x >> 3, seg = blockIdx.x & 7;   // 64 rb x 8 segs
    const int tid = threadIdx.x, wave = tid >> 6, lane = tid & 63;
    const int g = lane >> 5, cc = lane & 31;
    if (blockIdx.x == 0 && b == 0 && tid < 2) out[tid] = 0.0f;
    const float* qp = src + (size_t)b * NPTS * 3;   // rows = src
    const float* pp = tgt + (size_t)b * NPTS * 3;   // cols = tgt
    const unsigned short one = 0x3F80;

    __shared__ alignas(16) unsigned char smem[32768];   // 2 x 16 KB stage; epilogue alias
    __shared__ unsigned int colsmax[512];               // biased col s-max, this chunk
    float* scratch = (float*)smem;

    // ---- A fragments: 2 row-tiles/wave; -hq embedded in k 12-14 ----
    const int rt0 = rowblock * 8 + wave * 2;
    bf16x8 afrag[2];
#pragma unroll
    for (int i = 0; i < 2; i++) {
        int r = (rt0 + i) * 32 + cc;
        float x = qp[r * 3 + 0], y = qp[r * 3 + 1], z = qp[r * 3 + 2];
        float hq = 0.5f * fmaf(z, z, fmaf(y, y, x * x));
        unsigned short xh = f2bf(x), yh = f2bf(y), zh = f2bf(z);
        unsigned short xl = f2bf(x - bf2f(xh)), yl = f2bf(y - bf2f(yh)), zl = f2bf(z - bf2f(zh));
        float rr = hq;
        unsigned short h0 = f2bf(rr); rr -= bf2f(h0);
        unsigned short h1 = f2bf(rr); rr -= bf2f(h1);
        unsigned short h2 = f2bf(rr);
        UV f0, f1, rv;
        f0.s[0]=xh; f0.s[1]=yh; f0.s[2]=zh; f0.s[3]=xl; f0.s[4]=yl; f0.s[5]=zl; f0.s[6]=xh; f0.s[7]=yh;
        f1.s[0]=zh; f1.s[1]=one; f1.s[2]=one; f1.s[3]=one;
        f1.s[4]=(unsigned short)(h0^0x8000); f1.s[5]=(unsigned short)(h1^0x8000);
        f1.s[6]=(unsigned short)(h2^0x8000); f1.s[7]=0;
        rv.v = g ? f1.v : f0.v;
        afrag[i] = rv.h;
    }

    f32x16 m0 = -3.0e38f, m1 = -3.0e38f;
    const f32x16 zc = 0.0f;
    float px0, py0, pz0, px1, py1, pz1;

    colsmax[tid] = 0u; colsmax[tid + 256] = 0u;
    LOAD_PTS(0)
    CONV_WRITE(0)
    __syncthreads();
#pragma unroll 1
    for (int c = 0; c < 4; ++c) {                 // 4 chunks x 16 col-tiles
        if (c < 3) LOAD_PTS(c + 1)
        const unsigned short* bb = (const unsigned short*)(smem + (c & 1) * 16384);
#pragma unroll 1
        for (int pt = 0; pt < 8; ++pt) {          // 2 col-tiles per iter
            bf16x8 q0 = *(const bf16x8*)(bb + pt * 1024 + lane * 8);
            bf16x8 q1 = *(const bf16x8*)(bb + pt * 1024 + 512 + lane * 8);
            float ca = -3.0e38f, cb = -3.0e38f;
            FOLDC(m0, afrag[0], ca, cb)
            FOLDC(m1, afrag[1], ca, cb)
            atomicMax(&colsmax[pt * 64 + cc],      __float_as_uint(ca + 256.0f));
            atomicMax(&colsmax[pt * 64 + 32 + cc], __float_as_uint(cb + 256.0f));
        }
        __syncthreads();                          // all waves' folds+ds_max for chunk c done
        {   // flush col partials for this chunk (each thread owns 2 slots), re-init
            unsigned v0 = colsmax[tid], v1 = colsmax[tid + 256];
            colsmax[tid] = 0u; colsmax[tid + 256] = 0u;
            float s0 = __uint_as_float(v0) - 256.0f;
            float s1 = __uint_as_float(v1) - 256.0f;
            float dd0 = fminf(sqrtf(fmaxf(-2.0f * s0, 0.0f)), TH);
            float dd1 = fminf(sqrtf(fmaxf(-2.0f * s1, 0.0f)), TH);
            unsigned int* gc = colmin_g + (size_t)b * NPTS + seg * 2048 + c * 512;
            atomicMin(&gc[tid],       __float_as_uint(dd0));
            atomicMin(&gc[tid + 256], __float_as_uint(dd1));
        }
        if (c < 3) CONV_WRITE((c + 1) & 1)        // THE FIX: BUF = (c+1)&1 (R19 wrote c+1)
        __syncthreads();                          // stage + colsmax re-init visible
    }

    float* dst = row_part + ((size_t)(b * 64 + rowblock) * 8 + seg) * 256;
    EPILOG(m0, 0)
    EPILOG(m1, 1)
}

__global__ __launch_bounds__(256) void merge_kernel(const float* __restrict__ row_part,
        const unsigned int* __restrict__ colmin_g, float* __restrict__ out) {
    const int b = blockIdx.y;                     // batch
    const int slice = blockIdx.x;                 // 16 slices of 1024
    const int tid = threadIdx.x;
    float s = 0.0f;
#pragma unroll
    for (int i = 0; i < 4; i++) {
        int r = slice * 1024 + i * 256 + tid;
        const float* p = row_part + ((size_t)(b * 64 + (r >> 8)) * 8) * 256 + (r & 255);
        float m = p[0];
#pragma unroll
        for (int sg = 1; sg < 8; sg++) m = fminf(m, p[sg * 256]);
        s += m;                                               // dir0: src row-min
        s += __uint_as_float(colmin_g[(size_t)b * NPTS + r]); // dir1: tgt col-min
    }
#pragma unroll
    for (int off = 32; off > 0; off >>= 1) s += __shfl_down(s, off, 64);
    __shared__ float w[4];
    if ((tid & 63) == 0) w[tid >> 6] = s;
    __syncthreads();
    if (tid == 0) {
        float t = (w[0] + w[1]) + (w[2] + w[3]);
        atomicAdd(&out[b], t * (1.0f / (2.0f * NPTS)));   // (mean_fwd + mean_bwd) / 2
    }
}

extern "C" void kernel_launch(void* const* d_in, const int* in_sizes, int n_in,
                              void* d_out, int out_size, void* d_ws, size_t ws_size,
                              hipStream_t stream) {
    const float* src = (const float*)d_in[0];
    const float* tgt = (const float*)d_in[1];
    float* out = (float*)d_out;
    float* row_part = (float*)d_ws;                                   // 1 MB, write-once
    unsigned int* colmin_g = (unsigned int*)((char*)d_ws + 1048576);  // 128 KB

    hipMemsetAsync(colmin_g, 0xFF, 2 * NPTS * sizeof(unsigned int), stream);
    chamfer_kernel<<<dim3(512, 2), 256, 0, stream>>>(src, tgt, row_part, colmin_g, out);
    merge_kernel<<<dim3(16, 2), 256, 0, stream>>>(row_part, colmin_g, out);
}